// Round 1
// baseline (2929.937 us; speedup 1.0000x reference)
//
#include <hip/hip_runtime.h>
#include <hip/hip_bf16.h>
#include <math.h>

#define DEVI __device__ __forceinline__

typedef __attribute__((ext_vector_type(4))) float f32x4;
typedef __attribute__((ext_vector_type(8))) short s16x8;

DEVI float bf2f(ushort u){ union{unsigned int i; float f;} x; x.i = ((unsigned int)u)<<16; return x.f; }
DEVI ushort f2bf(float f){ union{float f; unsigned int i;} x; x.f = f;
  unsigned int r = x.i + 0x7fffu + ((x.i>>16)&1u); return (ushort)(r>>16); }

// ---------------- fp32 -> bf16 convert, 4 elems/thread ----------------
__global__ __launch_bounds__(256) void cvt_bf16(const float* __restrict__ in, ushort* __restrict__ out){
  int i = blockIdx.x*256 + threadIdx.x;
  float4 v = ((const float4*)in)[i];
  ushort4 o; o.x = f2bf(v.x); o.y = f2bf(v.y); o.z = f2bf(v.z); o.w = f2bf(v.w);
  ((ushort4*)out)[i] = o;
}

// ---------------- bf16 MFMA GEMM: C[M,N] = A[M,K] * B[N,K]^T ----------------
// 128x128 tile, BK=32, 256 threads (4 waves, each 64x64 = 4x4 MFMA 16x16x32 tiles),
// global_load_lds width-16 staging (m97 structure).
DEVI void gl_lds16(const ushort* g, ushort* l){
  __builtin_amdgcn_global_load_lds((const __attribute__((address_space(1))) void*)g,
                                   (__attribute__((address_space(3))) void*)l, 16, 0, 0);
}

template<int BF16_OUT>
__global__ __launch_bounds__(256, 2) void gemm_bt(const ushort* __restrict__ A,
                                                  const ushort* __restrict__ B,
                                                  void* __restrict__ Cv,
                                                  int M, int N, int K){
  __shared__ ushort As[128*32];
  __shared__ ushort Bs[128*32];
  const int nb = N >> 7;
  const int tile_m = (blockIdx.x / nb) << 7;
  const int tile_n = (blockIdx.x % nb) << 7;
  const int tid  = threadIdx.x;
  const int w    = tid >> 6;
  const int lane = tid & 63;

  // staging: wave w loads 1KB chunks {2w, 2w+1} of A-tile and B-tile.
  // chunk c = rows [16c,16c+16) x 32 bf16; lane L -> row L/4, 16B piece L%4.
  const int ca = w*2;
  const long rowA = tile_m + ca*16 + (lane>>2);
  const long rowB = tile_n + ca*16 + (lane>>2);
  const int  colE = (lane&3)*8;
  const ushort* pA0 = A + rowA*(long)K + colE;
  const ushort* pA1 = pA0 + 16l*K;
  const ushort* pB0 = B + rowB*(long)K + colE;
  const ushort* pB1 = pB0 + 16l*K;
  ushort* lA0 = As + ca*512;
  ushort* lA1 = As + ca*512 + 512;
  ushort* lB0 = Bs + ca*512;
  ushort* lB1 = Bs + ca*512 + 512;

  const int wr = (w>>1)<<6;          // wave row offset (0/64)
  const int wc = (w&1)<<6;           // wave col offset (0/64)
  const int fr = lane & 15;          // fragment row
  const int fk = (lane>>4)<<3;       // fragment k offset (0/8/16/24)

  f32x4 acc[4][4];
  #pragma unroll
  for (int i=0;i<4;i++)
    #pragma unroll
    for (int j=0;j<4;j++) acc[i][j] = (f32x4){0.f,0.f,0.f,0.f};

  for (int k0 = 0; k0 < K; k0 += 32){
    __syncthreads();                 // previous iter's ds_reads done before overwrite
    gl_lds16(pA0, lA0);
    gl_lds16(pA1, lA1);
    gl_lds16(pB0, lB0);
    gl_lds16(pB1, lB1);
    __syncthreads();                 // compiler emits vmcnt(0) drain before barrier
    s16x8 af[4], bfr[4];
    #pragma unroll
    for (int t=0;t<4;t++){
      af[t]  = *(const s16x8*)(As + (wr + t*16 + fr)*32 + fk);
      bfr[t] = *(const s16x8*)(Bs + (wc + t*16 + fr)*32 + fk);
    }
    #pragma unroll
    for (int mt=0;mt<4;mt++)
      #pragma unroll
      for (int nt=0;nt<4;nt++)
        acc[mt][nt] = __builtin_amdgcn_mfma_f32_16x16x32_bf16(af[mt], bfr[nt], acc[mt][nt], 0, 0, 0);
    pA0 += 32; pA1 += 32; pB0 += 32; pB1 += 32;
  }

  // C/D layout: col = lane&15, row = (lane>>4)*4 + reg  [m89/m91 verified]
  const int crow = tile_m + wr + ((lane>>4)<<2);
  const int ccol = tile_n + wc + (lane&15);
  if (BF16_OUT){
    ushort* C = (ushort*)Cv;
    #pragma unroll
    for (int mt=0;mt<4;mt++)
      #pragma unroll
      for (int r=0;r<4;r++){
        long row = crow + mt*16 + r;
        #pragma unroll
        for (int nt=0;nt<4;nt++)
          C[row*(long)N + ccol + nt*16] = f2bf(acc[mt][nt][r]);
      }
  } else {
    float* C = (float*)Cv;
    #pragma unroll
    for (int mt=0;mt<4;mt++)
      #pragma unroll
      for (int r=0;r<4;r++){
        long row = crow + mt*16 + r;
        #pragma unroll
        for (int nt=0;nt<4;nt++)
          C[row*(long)N + ccol + nt*16] = acc[mt][nt][r];
      }
  }
}

// ---------------- beta/gamma small projection (fp32 precise) ----------------
__global__ __launch_bounds__(256) void proj_ba(const float* __restrict__ X,
    const float* __restrict__ Wb, const float* __restrict__ Wa,
    const float* __restrict__ dtb, const float* __restrict__ alog,
    float* __restrict__ beta, float* __restrict__ gam){
  __shared__ float xs[2048];
  __shared__ float rb[256], ra[256];
  const int m = blockIdx.x;
  const float* xr = X + (long)m*2048;
  for (int i = threadIdx.x; i < 512; i += 256)
    ((float4*)xs)[i] = ((const float4*)xr)[i];
  __syncthreads();
  const int n = threadIdx.x & 31, jc = threadIdx.x >> 5;   // 32 heads x 8 K-chunks
  const float* wb = Wb + n*2048 + jc*256;
  const float* wa = Wa + n*2048 + jc*256;
  const float* xc = xs + jc*256;
  float sb = 0.f, sa = 0.f;
  for (int i=0;i<256;i++){ float x = xc[i]; sb = fmaf(x, wb[i], sb); sa = fmaf(x, wa[i], sa); }
  rb[threadIdx.x] = sb; ra[threadIdx.x] = sa;
  __syncthreads();
  if (threadIdx.x < 32){
    float b = 0.f, a = 0.f;
    #pragma unroll
    for (int j=0;j<8;j++){ b += rb[threadIdx.x + 32*j]; a += ra[threadIdx.x + 32*j]; }
    beta[(long)m*32 + threadIdx.x] = 1.f/(1.f+expf(-b));
    float ap = a + dtb[threadIdx.x];
    float sp = (ap > 20.f) ? ap : log1pf(expf(ap));             // softplus
    gam[(long)m*32 + threadIdx.x] = expf(-expf(alog[threadIdx.x]) * sp);  // exp(g)
  }
}

// ---------------- causal depthwise conv(K=4) + silu + l2norm(q,k) ----------------
// grid (4096 tokens, 64 groups of 128 channels); q groups [0,16), k [16,32), v [32,64)
__global__ __launch_bounds__(128) void conv_qkv(const ushort* __restrict__ mixed,
    const float* __restrict__ convw, ushort* __restrict__ qn, ushort* __restrict__ kn,
    ushort* __restrict__ vv){
  const int m = blockIdx.x;
  const int g = blockIdx.y;
  const int s = m & 2047;
  const int c = (g<<7) + threadIdx.x;
  float acc = 0.f;
  #pragma unroll
  for (int j=0;j<4;j++){
    int so = s - 3 + j;
    if (so >= 0) acc += bf2f(mixed[(long)(m-3+j)*8192 + c]) * convw[c*4+j];
  }
  float y = acc / (1.f + expf(-acc));                 // silu
  if (g < 32){
    float ss = y*y;
    #pragma unroll
    for (int off=32; off; off>>=1) ss += __shfl_xor(ss, off);
    __shared__ float w2[2];
    if ((threadIdx.x&63)==0) w2[threadIdx.x>>6] = ss;
    __syncthreads();
    float r = rsqrtf(w2[0] + w2[1] + 1e-6f);
    if (g < 16) qn[(long)m*2048 + c]          = f2bf(y*r*0.08838834764831845f); // * DK^-0.5
    else        kn[(long)m*2048 + (c-2048)]   = f2bf(y*r);
  } else {
    vv[(long)m*4096 + (c-4096)] = f2bf(y);
  }
}

// ---------------- gated delta-rule scan ----------------
// 256 blocks: block = part(0..3)*?? -> bid = part*64 + bh, so 4 parts of a head share an XCD.
// Each block owns 32 DV-columns of (b,h); thread patch = 8 k-rows x 2 cols in registers.
__global__ __launch_bounds__(256) void scan_k(const ushort* __restrict__ qn,
    const ushort* __restrict__ kn, const ushort* __restrict__ vv,
    const float* __restrict__ beta, const float* __restrict__ gam,
    float* __restrict__ o){
  const int bh = blockIdx.x & 63;
  const int part = blockIdx.x >> 6;
  const int b = bh >> 5, h = bh & 31, hq = h >> 1;
  const int tid = threadIdx.x;
  const int kr = tid & 15;          // k-range: rows [kr*8, kr*8+8)
  const int cp = tid >> 4;          // col-pair: cols part*32 + 2cp + {0,1}

  __shared__ float kq[2][256];      // k[128] | q[128], double-buffered
  __shared__ float vs[2][32];

  float st[8][2] = {};              // state patch (fp32)

  const long mb = (long)b*2048;
  const ushort* kptr = kn + mb*2048 + hq*128;
  const ushort* qptr = qn + mb*2048 + hq*128;
  const ushort* vptr = vv + mb*4096 + h*128 + part*32;
  const float* bptr = beta + mb*32 + h;
  const float* gptr = gam  + mb*32 + h;
  float* optr = o + (mb*32 + h)*128 + part*32 + 2*cp;

  for (int s=0; s<2048; s++){
    const int buf = s & 1;
    if (tid < 128) kq[buf][tid] = bf2f(kptr[tid]);
    else           kq[buf][tid] = bf2f(qptr[tid-128]);
    if (tid < 32)  vs[buf][tid] = bf2f(vptr[tid]);
    const float gm = *gptr;
    const float bt = *bptr;
    __syncthreads();
    float kf[8], qf[8];
    *(float4*)(kf)   = *(const float4*)&kq[buf][kr*8];
    *(float4*)(kf+4) = *(const float4*)&kq[buf][kr*8+4];
    *(float4*)(qf)   = *(const float4*)&kq[buf][128+kr*8];
    *(float4*)(qf+4) = *(const float4*)&kq[buf][128+kr*8+4];
    const float v0 = vs[buf][2*cp], v1 = vs[buf][2*cp+1];
    float m0 = 0.f, m1 = 0.f;
    #pragma unroll
    for (int j=0;j<8;j++){
      st[j][0] *= gm; st[j][1] *= gm;
      m0 = fmaf(kf[j], st[j][0], m0);
      m1 = fmaf(kf[j], st[j][1], m1);
    }
    #pragma unroll
    for (int off=1; off<16; off<<=1){ m0 += __shfl_xor(m0, off); m1 += __shfl_xor(m1, off); }
    const float d0 = (v0 - m0)*bt;
    const float d1 = (v1 - m1)*bt;
    float o0 = 0.f, o1 = 0.f;
    #pragma unroll
    for (int j=0;j<8;j++){
      st[j][0] = fmaf(kf[j], d0, st[j][0]);
      st[j][1] = fmaf(kf[j], d1, st[j][1]);
      o0 = fmaf(qf[j], st[j][0], o0);
      o1 = fmaf(qf[j], st[j][1], o1);
    }
    #pragma unroll
    for (int off=1; off<16; off<<=1){ o0 += __shfl_xor(o0, off); o1 += __shfl_xor(o1, off); }
    if (kr == 0){ optr[0] = o0; optr[1] = o1; }
    kptr += 2048; qptr += 2048; vptr += 4096; bptr += 32; gptr += 32; optr += 4096;
  }
}

// ---------------- RMSNorm(gated) + silu(z) gate, bf16 out ----------------
__global__ __launch_bounds__(128) void norm_gate(const float* __restrict__ o,
    const ushort* __restrict__ z, const float* __restrict__ normw,
    ushort* __restrict__ og){
  const long mh = blockIdx.x;
  const int d = threadIdx.x;
  float x = o[mh*128 + d];
  float ss = x*x;
  #pragma unroll
  for (int off=32; off; off>>=1) ss += __shfl_xor(ss, off);
  __shared__ float w2[2];
  if ((d&63)==0) w2[d>>6] = ss;
  __syncthreads();
  float r = rsqrtf((w2[0]+w2[1])*(1.f/128.f) + 1e-6f);
  float zz = bf2f(z[mh*128 + d]);
  float sil = zz / (1.f + expf(-zz));
  og[mh*128 + d] = f2bf(x*r*normw[d]*sil);
}

extern "C" void kernel_launch(void* const* d_in, const int* in_sizes, int n_in,
                              void* d_out, int out_size, void* d_ws, size_t ws_size,
                              hipStream_t stream){
  const float* hs    = (const float*)d_in[0];
  const float* Wqkv  = (const float*)d_in[1];
  const float* Wz    = (const float*)d_in[2];
  const float* Wb    = (const float*)d_in[3];
  const float* Wa    = (const float*)d_in[4];
  const float* convw = (const float*)d_in[5];
  const float* normw = (const float*)d_in[6];
  const float* Wout  = (const float*)d_in[7];
  const float* dtb   = (const float*)d_in[8];
  const float* alog  = (const float*)d_in[9];

  char* ws = (char*)d_ws;
  // 178 MiB total, with stream-ordered buffer reuse:
  ushort* hsb   = (ushort*)(ws);                 // [0,16M)    hs bf16  -> later kn
  ushort* wqb   = (ushort*)(ws + (16l<<20));     // [16,48M)   Wqkv bf16 -> later v -> og
  ushort* wzb   = (ushort*)(ws + (48l<<20));     // [48,64M)   Wz bf16  -> later qn
  ushort* wob   = (ushort*)(ws + (64l<<20));     // [64,80M)   Wout bf16
  ushort* mixed = (ushort*)(ws + (80l<<20));     // [80,144M)  mixed bf16 -> later o_raw f32
  ushort* zb    = (ushort*)(ws + (144l<<20));    // [144,176M) z bf16
  float*  beta  = (float*)(ws + (176l<<20));
  float*  gam   = (float*)(ws + (177l<<20));
  ushort* kn = hsb;  ushort* qn = wzb;  ushort* vvp = wqb;  ushort* og = wqb;
  float*  o_raw = (float*)mixed;

  cvt_bf16<<<8192,  256, 0, stream>>>(hs,   hsb);
  cvt_bf16<<<16384, 256, 0, stream>>>(Wqkv, wqb);
  cvt_bf16<<<8192,  256, 0, stream>>>(Wz,   wzb);
  cvt_bf16<<<8192,  256, 0, stream>>>(Wout, wob);

  gemm_bt<1><<<32*64, 256, 0, stream>>>(hsb, wqb, (void*)mixed, 4096, 8192, 2048);
  gemm_bt<1><<<32*32, 256, 0, stream>>>(hsb, wzb, (void*)zb,    4096, 4096, 2048);
  proj_ba<<<4096, 256, 0, stream>>>(hs, Wb, Wa, dtb, alog, beta, gam);

  conv_qkv<<<dim3(4096,64), 128, 0, stream>>>(mixed, convw, qn, kn, vvp);
  scan_k<<<256, 256, 0, stream>>>(qn, kn, vvp, beta, gam, o_raw);
  norm_gate<<<131072, 128, 0, stream>>>(o_raw, zb, normw, og);

  gemm_bt<0><<<32*16, 256, 0, stream>>>(og, wob, d_out, 4096, 2048, 4096);
}

// Round 2
// 1746.357 us; speedup vs baseline: 1.6777x; 1.6777x over previous
//
#include <hip/hip_runtime.h>
#include <hip/hip_bf16.h>
#include <math.h>

#define DEVI __device__ __forceinline__

typedef __attribute__((ext_vector_type(4))) float f32x4;
typedef __attribute__((ext_vector_type(8))) short s16x8;
typedef __attribute__((ext_vector_type(4))) unsigned int u32x4;

DEVI float bf2f(ushort u){ union{unsigned int i; float f;} x; x.i = ((unsigned int)u)<<16; return x.f; }
DEVI ushort f2bf(float f){ union{float f; unsigned int i;} x; x.f = f;
  unsigned int r = x.i + 0x7fffu + ((x.i>>16)&1u); return (ushort)(r>>16); }

// ---------------- fp32 -> bf16 convert, 4 elems/thread ----------------
__global__ __launch_bounds__(256) void cvt_bf16(const float* __restrict__ in, ushort* __restrict__ out){
  int i = blockIdx.x*256 + threadIdx.x;
  float4 v = ((const float4*)in)[i];
  ushort4 o; o.x = f2bf(v.x); o.y = f2bf(v.y); o.z = f2bf(v.z); o.w = f2bf(v.w);
  ((ushort4*)out)[i] = o;
}

// ---------------- bf16 MFMA GEMM: C[M,N] = A[M,K] * B[N,K]^T ----------------
// 128x128 tile, BK=32, 256 threads (4 waves, each 64x64 = 4x4 MFMA 16x16x32 tiles),
// global_load_lds width-16 staging (m97 structure).
DEVI void gl_lds16(const ushort* g, ushort* l){
  __builtin_amdgcn_global_load_lds((const __attribute__((address_space(1))) void*)g,
                                   (__attribute__((address_space(3))) void*)l, 16, 0, 0);
}

template<int BF16_OUT>
__global__ __launch_bounds__(256, 2) void gemm_bt(const ushort* __restrict__ A,
                                                  const ushort* __restrict__ B,
                                                  void* __restrict__ Cv,
                                                  int M, int N, int K){
  __shared__ ushort As[128*32];
  __shared__ ushort Bs[128*32];
  const int nb = N >> 7;
  const int tile_m = (blockIdx.x / nb) << 7;
  const int tile_n = (blockIdx.x % nb) << 7;
  const int tid  = threadIdx.x;
  const int w    = tid >> 6;
  const int lane = tid & 63;

  const int ca = w*2;
  const long rowA = tile_m + ca*16 + (lane>>2);
  const long rowB = tile_n + ca*16 + (lane>>2);
  const int  colE = (lane&3)*8;
  const ushort* pA0 = A + rowA*(long)K + colE;
  const ushort* pA1 = pA0 + 16l*K;
  const ushort* pB0 = B + rowB*(long)K + colE;
  const ushort* pB1 = pB0 + 16l*K;
  ushort* lA0 = As + ca*512;
  ushort* lA1 = As + ca*512 + 512;
  ushort* lB0 = Bs + ca*512;
  ushort* lB1 = Bs + ca*512 + 512;

  const int wr = (w>>1)<<6;          // wave row offset (0/64)
  const int wc = (w&1)<<6;           // wave col offset (0/64)
  const int fr = lane & 15;          // fragment row
  const int fk = (lane>>4)<<3;       // fragment k offset (0/8/16/24)

  f32x4 acc[4][4];
  #pragma unroll
  for (int i=0;i<4;i++)
    #pragma unroll
    for (int j=0;j<4;j++) acc[i][j] = (f32x4){0.f,0.f,0.f,0.f};

  for (int k0 = 0; k0 < K; k0 += 32){
    __syncthreads();
    gl_lds16(pA0, lA0);
    gl_lds16(pA1, lA1);
    gl_lds16(pB0, lB0);
    gl_lds16(pB1, lB1);
    __syncthreads();
    s16x8 af[4], bfr[4];
    #pragma unroll
    for (int t=0;t<4;t++){
      af[t]  = *(const s16x8*)(As + (wr + t*16 + fr)*32 + fk);
      bfr[t] = *(const s16x8*)(Bs + (wc + t*16 + fr)*32 + fk);
    }
    #pragma unroll
    for (int mt=0;mt<4;mt++)
      #pragma unroll
      for (int nt=0;nt<4;nt++)
        acc[mt][nt] = __builtin_amdgcn_mfma_f32_16x16x32_bf16(af[mt], bfr[nt], acc[mt][nt], 0, 0, 0);
    pA0 += 32; pA1 += 32; pB0 += 32; pB1 += 32;
  }

  // C/D layout: col = lane&15, row = (lane>>4)*4 + reg  [m89/m91 verified]
  const int crow = tile_m + wr + ((lane>>4)<<2);
  const int ccol = tile_n + wc + (lane&15);
  if (BF16_OUT){
    ushort* C = (ushort*)Cv;
    #pragma unroll
    for (int mt=0;mt<4;mt++)
      #pragma unroll
      for (int r=0;r<4;r++){
        long row = crow + mt*16 + r;
        #pragma unroll
        for (int nt=0;nt<4;nt++)
          C[row*(long)N + ccol + nt*16] = f2bf(acc[mt][nt][r]);
      }
  } else {
    float* C = (float*)Cv;
    #pragma unroll
    for (int mt=0;mt<4;mt++)
      #pragma unroll
      for (int r=0;r<4;r++){
        long row = crow + mt*16 + r;
        #pragma unroll
        for (int nt=0;nt<4;nt++)
          C[row*(long)N + ccol + nt*16] = acc[mt][nt][r];
      }
  }
}

// ---------------- beta/gamma small projection (fp32 precise) ----------------
__global__ __launch_bounds__(256) void proj_ba(const float* __restrict__ X,
    const float* __restrict__ Wb, const float* __restrict__ Wa,
    const float* __restrict__ dtb, const float* __restrict__ alog,
    float* __restrict__ beta, float* __restrict__ gam){
  __shared__ float xs[2048];
  __shared__ float rb[256], ra[256];
  const int m = blockIdx.x;
  const float* xr = X + (long)m*2048;
  for (int i = threadIdx.x; i < 512; i += 256)
    ((float4*)xs)[i] = ((const float4*)xr)[i];
  __syncthreads();
  const int n = threadIdx.x & 31, jc = threadIdx.x >> 5;   // 32 heads x 8 K-chunks
  const float* wb = Wb + n*2048 + jc*256;
  const float* wa = Wa + n*2048 + jc*256;
  const float* xc = xs + jc*256;
  float sb = 0.f, sa = 0.f;
  for (int i=0;i<256;i++){ float x = xc[i]; sb = fmaf(x, wb[i], sb); sa = fmaf(x, wa[i], sa); }
  rb[threadIdx.x] = sb; ra[threadIdx.x] = sa;
  __syncthreads();
  if (threadIdx.x < 32){
    float b = 0.f, a = 0.f;
    #pragma unroll
    for (int j=0;j<8;j++){ b += rb[threadIdx.x + 32*j]; a += ra[threadIdx.x + 32*j]; }
    beta[(long)m*32 + threadIdx.x] = 1.f/(1.f+expf(-b));
    float ap = a + dtb[threadIdx.x];
    float sp = (ap > 20.f) ? ap : log1pf(expf(ap));             // softplus
    gam[(long)m*32 + threadIdx.x] = expf(-expf(alog[threadIdx.x]) * sp);  // exp(g)
  }
}

// ---------------- causal depthwise conv(K=4) + silu + l2norm(q,k) ----------------
__global__ __launch_bounds__(128) void conv_qkv(const ushort* __restrict__ mixed,
    const float* __restrict__ convw, ushort* __restrict__ qn, ushort* __restrict__ kn,
    ushort* __restrict__ vv){
  const int m = blockIdx.x;
  const int g = blockIdx.y;
  const int s = m & 2047;
  const int c = (g<<7) + threadIdx.x;
  float acc = 0.f;
  #pragma unroll
  for (int j=0;j<4;j++){
    int so = s - 3 + j;
    if (so >= 0) acc += bf2f(mixed[(long)(m-3+j)*8192 + c]) * convw[c*4+j];
  }
  float y = acc / (1.f + expf(-acc));                 // silu
  if (g < 32){
    float ss = y*y;
    #pragma unroll
    for (int off=32; off; off>>=1) ss += __shfl_xor(ss, off);
    __shared__ float w2[2];
    if ((threadIdx.x&63)==0) w2[threadIdx.x>>6] = ss;
    __syncthreads();
    float r = rsqrtf(w2[0] + w2[1] + 1e-6f);
    if (g < 16) qn[(long)m*2048 + c]          = f2bf(y*r*0.08838834764831845f); // * DK^-0.5
    else        kn[(long)m*2048 + (c-2048)]   = f2bf(y*r);
  } else {
    vv[(long)m*4096 + (c-4096)] = f2bf(y);
  }
}

// ---------------- DPP 16-lane butterfly sum (all lanes get total) ----------------
template<int CTRL>
DEVI float dpp_add(float x){
  int xi = __builtin_bit_cast(int, x);
  int yi = __builtin_amdgcn_update_dpp(xi, xi, CTRL, 0xf, 0xf, false);
  return x + __builtin_bit_cast(float, yi);
}
DEVI float red16(float x){
  x = dpp_add<0xB1>(x);    // quad_perm 1,0,3,2  (xor 1)
  x = dpp_add<0x4E>(x);    // quad_perm 2,3,0,1  (xor 2)
  x = dpp_add<0x124>(x);   // row_ror:4
  x = dpp_add<0x128>(x);   // row_ror:8
  return x;
}

DEVI void unpk(unsigned int u, float& a, float& b){
  union{unsigned int i; float f;} x, y;
  x.i = u << 16; y.i = u & 0xffff0000u;
  a = x.f; b = y.f;
}

// ---------------- gated delta-rule scan, barrier-free register version ----------------
// 512 blocks = part(0..7)*64 + bh. Block = 16 groups of 16 lanes; group g owns
// DV column c = part*16 + g of head (b,h). Lane kr owns k-rows [8kr, 8kr+8).
// State: 8 fp32 regs/thread. No LDS, no __syncthreads; reductions via DPP.
__global__ __launch_bounds__(256) void scan_k(const ushort* __restrict__ qn,
    const ushort* __restrict__ kn, const ushort* __restrict__ vv,
    const float* __restrict__ beta, const float* __restrict__ gam,
    float* __restrict__ o){
  const int bh = blockIdx.x & 63;
  const int part = blockIdx.x >> 6;      // 0..7
  const int b = bh >> 5, h = bh & 31, hq = h >> 1;
  const int tid = threadIdx.x;
  const int kr = tid & 15;
  const int grp = tid >> 4;              // 0..15
  const int c = part*16 + grp;           // DV column

  const long mb = (long)b*2048;
  const ushort* kptr = kn + mb*2048 + hq*128 + kr*8;
  const ushort* qptr = qn + mb*2048 + hq*128 + kr*8;
  const ushort* vptr = vv + mb*4096 + h*128 + c;
  const float*  bptr = beta + mb*32 + h;
  const float*  gptr = gam  + mb*32 + h;
  float* optr = o + (mb*32 + h)*128 + c;

  float st[8] = {};

  // preload step 0
  u32x4 kc = *(const u32x4*)kptr;
  u32x4 qc = *(const u32x4*)qptr;
  float vc  = bf2f(*vptr);
  float btc = *bptr;
  float gmc = *gptr;

  for (int s = 0; s < 2048; s++){
    // prefetch step s+1 (last iter reads in-bounds scratch garbage, never used)
    u32x4 kp = *(const u32x4*)(kptr + 2048);
    u32x4 qp = *(const u32x4*)(qptr + 2048);
    float vp  = bf2f(vptr[4096]);
    float btp = bptr[32];
    float gmp = gptr[32];

    float kf[8], qf[8];
    unpk(kc[0], kf[0], kf[1]); unpk(kc[1], kf[2], kf[3]);
    unpk(kc[2], kf[4], kf[5]); unpk(kc[3], kf[6], kf[7]);
    unpk(qc[0], qf[0], qf[1]); unpk(qc[1], qf[2], qf[3]);
    unpk(qc[2], qf[4], qf[5]); unpk(qc[3], qf[6], qf[7]);

    // decay + mem = k . state   (4 accumulators to cut dep chain)
    float m0=0.f, m1=0.f, m2=0.f, m3=0.f;
    #pragma unroll
    for (int j=0;j<8;j++) st[j] *= gmc;
    m0 = fmaf(kf[0], st[0], m0); m1 = fmaf(kf[1], st[1], m1);
    m2 = fmaf(kf[2], st[2], m2); m3 = fmaf(kf[3], st[3], m3);
    m0 = fmaf(kf[4], st[4], m0); m1 = fmaf(kf[5], st[5], m1);
    m2 = fmaf(kf[6], st[6], m2); m3 = fmaf(kf[7], st[7], m3);
    float m = red16((m0+m1)+(m2+m3));

    const float d = (vc - m)*btc;

    // state += k*d ; o = q . state
    float o0=0.f, o1=0.f, o2=0.f, o3=0.f;
    #pragma unroll
    for (int j=0;j<8;j++) st[j] = fmaf(kf[j], d, st[j]);
    o0 = fmaf(qf[0], st[0], o0); o1 = fmaf(qf[1], st[1], o1);
    o2 = fmaf(qf[2], st[2], o2); o3 = fmaf(qf[3], st[3], o3);
    o0 = fmaf(qf[4], st[4], o0); o1 = fmaf(qf[5], st[5], o1);
    o2 = fmaf(qf[6], st[6], o2); o3 = fmaf(qf[7], st[7], o3);
    float oo = red16((o0+o1)+(o2+o3));

    if (kr == 0) *optr = oo;

    kc = kp; qc = qp; vc = vp; btc = btp; gmc = gmp;
    kptr += 2048; qptr += 2048; vptr += 4096; bptr += 32; gptr += 32; optr += 4096;
  }
}

// ---------------- RMSNorm(gated) + silu(z) gate, bf16 out ----------------
__global__ __launch_bounds__(128) void norm_gate(const float* __restrict__ o,
    const ushort* __restrict__ z, const float* __restrict__ normw,
    ushort* __restrict__ og){
  const long mh = blockIdx.x;
  const int d = threadIdx.x;
  float x = o[mh*128 + d];
  float ss = x*x;
  #pragma unroll
  for (int off=32; off; off>>=1) ss += __shfl_xor(ss, off);
  __shared__ float w2[2];
  if ((d&63)==0) w2[d>>6] = ss;
  __syncthreads();
  float r = rsqrtf((w2[0]+w2[1])*(1.f/128.f) + 1e-6f);
  float zz = bf2f(z[mh*128 + d]);
  float sil = zz / (1.f + expf(-zz));
  og[mh*128 + d] = f2bf(x*r*normw[d]*sil);
}

extern "C" void kernel_launch(void* const* d_in, const int* in_sizes, int n_in,
                              void* d_out, int out_size, void* d_ws, size_t ws_size,
                              hipStream_t stream){
  const float* hs    = (const float*)d_in[0];
  const float* Wqkv  = (const float*)d_in[1];
  const float* Wz    = (const float*)d_in[2];
  const float* Wb    = (const float*)d_in[3];
  const float* Wa    = (const float*)d_in[4];
  const float* convw = (const float*)d_in[5];
  const float* normw = (const float*)d_in[6];
  const float* Wout  = (const float*)d_in[7];
  const float* dtb   = (const float*)d_in[8];
  const float* alog  = (const float*)d_in[9];

  char* ws = (char*)d_ws;
  ushort* hsb   = (ushort*)(ws);                 // [0,16M)    hs bf16  -> later kn
  ushort* wqb   = (ushort*)(ws + (16l<<20));     // [16,48M)   Wqkv bf16 -> later v -> og
  ushort* wzb   = (ushort*)(ws + (48l<<20));     // [48,64M)   Wz bf16  -> later qn
  ushort* wob   = (ushort*)(ws + (64l<<20));     // [64,80M)   Wout bf16
  ushort* mixed = (ushort*)(ws + (80l<<20));     // [80,144M)  mixed bf16 -> later o_raw f32
  ushort* zb    = (ushort*)(ws + (144l<<20));    // [144,176M) z bf16
  float*  beta  = (float*)(ws + (176l<<20));
  float*  gam   = (float*)(ws + (177l<<20));
  ushort* kn = hsb;  ushort* qn = wzb;  ushort* vvp = wqb;  ushort* og = wqb;
  float*  o_raw = (float*)mixed;

  cvt_bf16<<<8192,  256, 0, stream>>>(hs,   hsb);
  cvt_bf16<<<16384, 256, 0, stream>>>(Wqkv, wqb);
  cvt_bf16<<<8192,  256, 0, stream>>>(Wz,   wzb);
  cvt_bf16<<<8192,  256, 0, stream>>>(Wout, wob);

  gemm_bt<1><<<32*64, 256, 0, stream>>>(hsb, wqb, (void*)mixed, 4096, 8192, 2048);
  gemm_bt<1><<<32*32, 256, 0, stream>>>(hsb, wzb, (void*)zb,    4096, 4096, 2048);
  proj_ba<<<4096, 256, 0, stream>>>(hs, Wb, Wa, dtb, alog, beta, gam);

  conv_qkv<<<dim3(4096,64), 128, 0, stream>>>(mixed, convw, qn, kn, vvp);
  scan_k<<<512, 256, 0, stream>>>(qn, kn, vvp, beta, gam, o_raw);
  norm_gate<<<131072, 128, 0, stream>>>(o_raw, zb, normw, og);

  gemm_bt<0><<<32*16, 256, 0, stream>>>(og, wob, d_out, 4096, 2048, 4096);
}